// Round 10
// baseline (91.989 us; speedup 1.0000x reference)
//
#include <hip/hip_runtime.h>

// B=2, S=2048, D=1024, H=16, HD=64. K == Q (xk = x@Wq.T, same RoPE).
// Pipeline: fused f32->bf16 convert -> merged GEMM (R7 mapping):
//   [x@Wq.T + RoPE -> Kf frag-layout], [x@Wv.T -> Vf frag-layout]
// -> flash attention, no LDS/barriers in main loop, frag loads coalesced.
// R10: attn = 64 q-rows/wave (4 qs), grid 512, balanced qb pairing, NO
//   setprio. Strict liveness schedule to avoid R8's spill: single sa/cpk
//   reused across the two q-groups; macro-constant indices (rule #20).

typedef float f32x4 __attribute__((ext_vector_type(4)));
typedef short s16x8 __attribute__((ext_vector_type(8)));

__device__ inline unsigned short f2bf(float f) {
  union { float f; unsigned u; } v; v.f = f;
  unsigned r = v.u + 0x7FFFu + ((v.u >> 16) & 1u);
  return (unsigned short)(r >> 16);
}

__device__ inline void gload16(const unsigned short* g, unsigned short* l) {
  __builtin_amdgcn_global_load_lds(
      (const __attribute__((address_space(1))) unsigned int*)g,
      (__attribute__((address_space(3))) unsigned int*)l, 16, 0, 0);
}

__global__ __launch_bounds__(256) void convert_all(
    const float* __restrict__ x, const float* __restrict__ wq,
    const float* __restrict__ wv, unsigned short* __restrict__ xb,
    unsigned short* __restrict__ wqb, unsigned short* __restrict__ wvb) {
  int i = blockIdx.x * 256 + threadIdx.x;
  const float* src; unsigned short* dst; int off;
  if (i < 1048576) { src = x; dst = xb; off = i; }
  else if (i < 1310720) { src = wq; dst = wqb; off = i - 1048576; }
  else { src = wv; dst = wvb; off = i - 1310720; }
  float4 v = ((const float4*)src)[off];
  ushort4 o;
  o.x = f2bf(v.x); o.y = f2bf(v.y); o.z = f2bf(v.z); o.w = f2bf(v.w);
  ((ushort4*)dst)[off] = o;
}

// Merged GEMM: grid 512. Blocks [0,256) -> Q-proj (+RoPE) -> Kf.
// Blocks [256,512) -> V-proj -> Vf.  M=4096 N=1024 K=1024, bf16, f32 acc.
__global__ __launch_bounds__(256, 2) void qv_gemm(
    const unsigned short* __restrict__ A, const unsigned short* __restrict__ Wq,
    const unsigned short* __restrict__ Wv, const float* __restrict__ cosT,
    const float* __restrict__ sinT, unsigned short* __restrict__ Kf,
    unsigned short* __restrict__ Vf) {
  __shared__ unsigned short GS[2][2][128][64];  // [buf][A/B][row][col] 64KB
  int tid = threadIdx.x;
  int isq = blockIdx.x < 256;
  int b256 = blockIdx.x & 255;
  int bm = b256 & 31, bn = b256 >> 5;
  int w = tid >> 6, lane = tid & 63, lr = lane & 15, lg = lane >> 4;
  int wm = w >> 1, wn = w & 1;
  int l8 = lane >> 3, l7 = lane & 7;
  f32x4 acc[4][4] = {};

  const unsigned short* Wp = isq ? Wq : Wv;
  const unsigned short* srcbase =
      (w < 2) ? (A + bm * 128 * 1024) : (Wp + bn * 128 * 1024);
  int ab = w >> 1;

  auto stage = [&](int step) {
    int buf = step & 1, kt = step * 64;
#pragma unroll
    for (int i = 0; i < 8; ++i) {
      int rgrp = (w & 1) * 8 + i;
      int u = rgrp * 8 + l8;
      int ch = l7 ^ (u & 7);
      gload16(srcbase + u * 1024 + kt + ch * 8,
              (unsigned short*)&GS[buf][ab][rgrp * 8][0]);
    }
  };

  stage(0);
  for (int step = 0; step < 16; ++step) {
    int buf = step & 1;
    asm volatile("s_waitcnt vmcnt(0)" ::: "memory");
    __syncthreads();
    if (step + 1 < 16) stage(step + 1);
    s16x8 af[4][2], bfr[4][2];
#pragma unroll
    for (int mf = 0; mf < 4; ++mf)
#pragma unroll
      for (int kk = 0; kk < 2; ++kk)
        af[mf][kk] = *(const s16x8*)
            &GS[buf][0][wm * 64 + mf * 16 + lr][((kk * 4 + lg) ^ (lr & 7)) * 8];
#pragma unroll
    for (int nf = 0; nf < 4; ++nf)
#pragma unroll
      for (int kk = 0; kk < 2; ++kk)
        bfr[nf][kk] = *(const s16x8*)
            &GS[buf][1][wn * 64 + nf * 16 + lr][((kk * 4 + lg) ^ (lr & 7)) * 8];
#pragma unroll
    for (int mf = 0; mf < 4; ++mf)
#pragma unroll
      for (int nf = 0; nf < 4; ++nf)
#pragma unroll
        for (int kk = 0; kk < 2; ++kk)
          acc[mf][nf] = __builtin_amdgcn_mfma_f32_16x16x32_bf16(
              af[mf][kk], bfr[nf][kk], acc[mf][nf], 0, 0, 0);
  }

  int mBase = bm * 128 + wm * 64;
  int nBase = bn * 128 + wn * 64;
  if (isq) {
    // RoPE, then per-wave LDS transpose -> coalesced dwordx4 Kf stores.
    __syncthreads();
    unsigned short* Lw = &GS[0][0][0][0] + w * (64 * 72);
    int bq = mBase >> 11;
    int sbase = mBase & 2047;
    int kt = sbase >> 6;
    int h = (nBase >> 6);
    int bh = bq * 16 + h;
#pragma unroll
    for (int mf = 0; mf < 4; ++mf)
#pragma unroll
      for (int j = 0; j < 4; ++j) {
        int sp = mf * 16 + 4 * lg + j;
        int s = sbase + sp;
#pragma unroll
        for (int nf = 0; nf < 4; ++nf) {
          int hd = nf * 16 + lr;
          float self = acc[mf][nf][j];
          float part = (nf < 2) ? -acc[mf][nf + 2][j] : acc[mf][nf - 2][j];
          float val = self * cosT[s * 64 + hd] + part * sinT[s * 64 + hd];
          Lw[sp * 72 + hd] = f2bf(val);
        }
      }
    asm volatile("s_waitcnt lgkmcnt(0)" ::: "memory");
    __builtin_amdgcn_sched_barrier(0);
    unsigned short* KfT = Kf + (size_t)(bh * 32 + kt) * 4096;
#pragma unroll
    for (int i = 0; i < 8; ++i) {
      int kk = i & 1, nfk = i >> 1;
      int lg2 = lane >> 4, lr2 = lane & 15;
      int sp = ((nfk >> 1) << 5) | ((lr2 >> 2) << 3) | ((nfk & 1) << 2) |
               (lr2 & 3);
      int c = kk * 4 + lg2;
      s16x8 vch = *(const s16x8*)&Lw[sp * 72 + c * 8];
      *(s16x8*)&KfT[(i * 64 + lane) * 8] = vch;
    }
  } else {
#pragma unroll
    for (int mf = 0; mf < 4; ++mf) {
      int m0 = mBase + mf * 16 + 4 * lg;
      int b = m0 >> 11, s0 = m0 & 2047;
      int kt = s0 >> 6, w0 = s0 & 63;
      int kkv = w0 >> 5, lg2 = (w0 >> 3) & 3, e0 = w0 & 7;
#pragma unroll
      for (int nf = 0; nf < 4; ++nf) {
        int col = nBase + nf * 16 + lr;
        int h = col >> 6;
        int bh = b * 16 + h;
        ushort4 pk;
        pk.x = f2bf(acc[mf][nf][0]); pk.y = f2bf(acc[mf][nf][1]);
        pk.z = f2bf(acc[mf][nf][2]); pk.w = f2bf(acc[mf][nf][3]);
        int idx2 = (((((bh * 32 + kt) * 4 + nf) * 2 + kkv) * 64) +
                    lg2 * 16 + lr) * 8 + e0;
        *(ushort4*)&Vf[idx2] = pk;
      }
    }
  }
}

// Per-group macros with LITERAL qs indices (rule #20: no runtime indexing).
#define MFMA_B16 __builtin_amdgcn_mfma_f32_16x16x32_bf16

#define QK_G(Q0, Q1)                                                       \
  {                                                                        \
    _Pragma("unroll") for (int q2 = 0; q2 < 2; ++q2)                       \
        _Pragma("unroll") for (int nf = 0; nf < 4; ++nf)                   \
            sa[q2][nf] = (f32x4){0.f, 0.f, 0.f, 0.f};                      \
    _Pragma("unroll") for (int kk = 0; kk < 2; ++kk)                       \
        _Pragma("unroll") for (int nf = 0; nf < 4; ++nf) {                 \
      sa[0][nf] = MFMA_B16(kf[nf][kk], aq[Q0][kk], sa[0][nf], 0, 0, 0);    \
      sa[1][nf] = MFMA_B16(kf[nf][kk], aq[Q1][kk], sa[1][nf], 0, 0, 0);    \
    }                                                                      \
  }

#define MASK_G(Q0, Q1, KT)                                                 \
  {                                                                        \
    _Pragma("unroll") for (int q2 = 0; q2 < 2; ++q2) {                     \
      int qglob = q0 + qh * 64 + 16 * (q2 ? (Q1) : (Q0)) + lr;             \
      _Pragma("unroll") for (int nf = 0; nf < 4; ++nf) {                   \
        int kc = (KT)*64 + 8 * lg + 4 * (nf & 1) + 32 * (nf >> 1);         \
        _Pragma("unroll") for (int j = 0; j < 4; ++j) if (kc + j > qglob)  \
            sa[q2][nf][j] = -3e38f;                                        \
      }                                                                    \
    }                                                                      \
  }

#define SM_G(Q0, Q1)                                                       \
  {                                                                        \
    float tm0, tm1;                                                        \
    {                                                                      \
      f32x4 t01 = __builtin_elementwise_max(sa[0][0], sa[0][1]);           \
      f32x4 t23 = __builtin_elementwise_max(sa[0][2], sa[0][3]);           \
      f32x4 t = __builtin_elementwise_max(t01, t23);                       \
      tm0 = fmaxf(fmaxf(t[0], t[1]), fmaxf(t[2], t[3]));                   \
      t01 = __builtin_elementwise_max(sa[1][0], sa[1][1]);                 \
      t23 = __builtin_elementwise_max(sa[1][2], sa[1][3]);                 \
      t = __builtin_elementwise_max(t01, t23);                             \
      tm1 = fmaxf(fmaxf(t[0], t[1]), fmaxf(t[2], t[3]));                   \
    }                                                                      \
    float worst = fmaxf(tm0 - m_[Q0], tm1 - m_[Q1]);                       \
    if (!__all(worst <= THR)) {                                            \
      float rm0 = fmaxf(tm0, __shfl_xor(tm0, 16));                         \
      rm0 = fmaxf(rm0, __shfl_xor(rm0, 32));                               \
      float mn0 = fmaxf(m_[Q0], rm0);                                      \
      float al0 = exp2f((m_[Q0] - mn0) * SC);                              \
      m_[Q0] = mn0; l_[Q0] *= al0;                                         \
      float rm1 = fmaxf(tm1, __shfl_xor(tm1, 16));                         \
      rm1 = fmaxf(rm1, __shfl_xor(rm1, 32));                               \
      float mn1 = fmaxf(m_[Q1], rm1);                                      \
      float al1 = exp2f((m_[Q1] - mn1) * SC);                              \
      m_[Q1] = mn1; l_[Q1] *= al1;                                         \
      _Pragma("unroll") for (int j = 0; j < 4; ++j) {                      \
        float a0j = __shfl(al0, 4 * lg + j);                               \
        float a1j = __shfl(al1, 4 * lg + j);                               \
        _Pragma("unroll") for (int nf = 0; nf < 4; ++nf) {                 \
          o[Q0][nf][j] *= a0j;                                             \
          o[Q1][nf][j] *= a1j;                                             \
        }                                                                  \
      }                                                                    \
    }                                                                      \
    {                                                                      \
      float msc = m_[Q0] * SC;                                             \
      _Pragma("unroll") for (int nf = 0; nf < 4; ++nf) {                   \
        float p0 = exp2f(fmaf(sa[0][nf][0], SC, -msc));                    \
        float p1 = exp2f(fmaf(sa[0][nf][1], SC, -msc));                    \
        float p2 = exp2f(fmaf(sa[0][nf][2], SC, -msc));                    \
        float p3 = exp2f(fmaf(sa[0][nf][3], SC, -msc));                    \
        l_[Q0] += (p0 + p1) + (p2 + p3);                                   \
        unsigned r0, r1;                                                   \
        asm("v_cvt_pk_bf16_f32 %0, %1, %2" : "=v"(r0) : "v"(p0), "v"(p1)); \
        asm("v_cvt_pk_bf16_f32 %0, %1, %2" : "=v"(r1) : "v"(p2), "v"(p3)); \
        cpk[0][nf * 2] = r0; cpk[0][nf * 2 + 1] = r1;                      \
      }                                                                    \
      msc = m_[Q1] * SC;                                                   \
      _Pragma("unroll") for (int nf = 0; nf < 4; ++nf) {                   \
        float p0 = exp2f(fmaf(sa[1][nf][0], SC, -msc));                    \
        float p1 = exp2f(fmaf(sa[1][nf][1], SC, -msc));                    \
        float p2 = exp2f(fmaf(sa[1][nf][2], SC, -msc));                    \
        float p3 = exp2f(fmaf(sa[1][nf][3], SC, -msc));                    \
        l_[Q1] += (p0 + p1) + (p2 + p3);                                   \
        unsigned r0, r1;                                                   \
        asm("v_cvt_pk_bf16_f32 %0, %1, %2" : "=v"(r0) : "v"(p0), "v"(p1)); \
        asm("v_cvt_pk_bf16_f32 %0, %1, %2" : "=v"(r1) : "v"(p2), "v"(p3)); \
        cpk[1][nf * 2] = r0; cpk[1][nf * 2 + 1] = r1;                      \
      }                                                                    \
    }                                                                      \
  }

#define PV_G(Q0, Q1)                                                       \
  {                                                                        \
    _Pragma("unroll") for (int kk = 0; kk < 2; ++kk) {                     \
      union { unsigned u[4]; s16x8 v; } pa0, pa1;                          \
      pa0.u[0] = cpk[0][4 * kk + 0]; pa0.u[1] = cpk[0][4 * kk + 1];        \
      pa0.u[2] = cpk[0][4 * kk + 2]; pa0.u[3] = cpk[0][4 * kk + 3];        \
      pa1.u[0] = cpk[1][4 * kk + 0]; pa1.u[1] = cpk[1][4 * kk + 1];        \
      pa1.u[2] = cpk[1][4 * kk + 2]; pa1.u[3] = cpk[1][4 * kk + 3];        \
      _Pragma("unroll") for (int nf = 0; nf < 4; ++nf) {                   \
        o[Q0][nf] = MFMA_B16(pa0.v, vf[nf][kk], o[Q0][nf], 0, 0, 0);       \
        o[Q1][nf] = MFMA_B16(pa1.v, vf[nf][kk], o[Q1][nf], 0, 0, 0);       \
      }                                                                    \
    }                                                                      \
  }

// Flash attention: block = 128 q-rows, wave = (q-half qh, k-parity par),
// each wave owns 64 q-rows (4 qs, two groups processed strictly in
// sequence to bound liveness). grid 512; balanced qb pairing; no LDS /
// barriers in main loop. Pairwise (par) merge via LDS at end.
__global__ __launch_bounds__(256) void attn(
    const unsigned short* __restrict__ Kf,  // frag layout
    const unsigned short* __restrict__ Vf,  // frag layout
    float* __restrict__ out) {              // [2][2048][1024]
  __shared__ float MB[2][4][4][16][17];
  __shared__ float ML[2][4][2][16];
  const float SC = 0.125f * 1.44269504088896f;  // scale * log2(e)
  const float THR = 44.0f;                      // ~= 8 / SC
  int tid = threadIdx.x;
  int fid = blockIdx.x;
  int bh = 4 * (fid & 7) + ((fid >> 3) & 3);
  int hi = fid >> 5;                       // 0..15
  int qb = (hi < 8) ? (15 - hi) : (hi - 8);  // CU pair {15-h0, h0}: balanced
  int w = tid >> 6, lane = tid & 63, lr = lane & 15, lg = lane >> 4;
  int q0 = qb * 128, qh = w >> 1, par = w & 1;

  const unsigned short* KfB = Kf + (size_t)bh * 32 * 4096;
  const unsigned short* VfB = Vf + (size_t)bh * 32 * 4096;

  // aq (B-operand) for 64 q-rows: 4 qs x 2 kk = 32 VGPR.
  s16x8 aq[4][2];
#pragma unroll
  for (int qs = 0; qs < 4; ++qs) {
    int qr = q0 + qh * 64 + 16 * qs + lr;
    int ktq = qr >> 6, w64 = qr & 63;
    int nfq = ((w64 >> 5) << 1) | ((w64 >> 2) & 1);
    int r31 = w64 & 31;
    int lr2 = ((r31 >> 3) << 2) | (r31 & 3);
#pragma unroll
    for (int kk = 0; kk < 2; ++kk)
      aq[qs][kk] = *(const s16x8*)
          &KfB[((((ktq * 4 + nfq) * 2 + kk) * 64) + lg * 16 + lr2) * 8];
  }

  f32x4 o[4][4] = {};
  float m_[4] = {-1e30f, -1e30f, -1e30f, -1e30f}, l_[4] = {0.f, 0.f, 0.f, 0.f};

  s16x8 kf[4][2], vf[4][2];
  auto loadK = [&](int kt_) {
#pragma unroll
    for (int nf = 0; nf < 4; ++nf)
#pragma unroll
      for (int kk = 0; kk < 2; ++kk)
        kf[nf][kk] = *(const s16x8*)
            &KfB[(((kt_ * 4 + nf) * 2 + kk) * 64 + lane) * 8];
  };
  auto loadV = [&](int kt_) {
#pragma unroll
    for (int nf = 0; nf < 4; ++nf)
#pragma unroll
      for (int kk = 0; kk < 2; ++kk)
        vf[nf][kk] = *(const s16x8*)
            &VfB[(((kt_ * 4 + nf) * 2 + kk) * 64 + lane) * 8];
  };

  int ktmax = 2 * qb + qh;  // diag tile for this wave's 64 rows
  int kt = par;
  bool active = kt <= ktmax;
  if (active) { loadK(kt); loadV(kt); }
  while (active) {
    bool diag = (kt == ktmax);
    f32x4 sa[2][4];
    unsigned cpk[2][8];
    int ktn = kt + 2;
    bool more = ktn <= ktmax;
    // group 0 (qs 0,1)
    QK_G(0, 1)
    if (diag) MASK_G(0, 1, kt)
    SM_G(0, 1)
    // group 1 (qs 2,3): last kf use, then refill kf
    QK_G(2, 3)
    if (more) loadK(ktn);  // lands during PV(g0)+SM(g1)+PV(g1)
    PV_G(0, 1)
    if (diag) MASK_G(2, 3, kt)
    SM_G(2, 3)
    PV_G(2, 3)
    if (more) loadV(ktn);  // lands during next QK(g0)+SM(g0)
    kt = ktn; active = more;
  }

  // merge: waves (qh,0) and (qh,1) share q-rows; odd writes, even merges.
#pragma unroll
  for (int qs = 0; qs < 4; ++qs) {
    float t = l_[qs];
    t += __shfl_xor(t, 16); t += __shfl_xor(t, 32);
    l_[qs] = t;
  }
  if (par) {
#pragma unroll
    for (int qs = 0; qs < 4; ++qs) {
#pragma unroll
      for (int nf = 0; nf < 4; ++nf)
#pragma unroll
        for (int j = 0; j < 4; ++j)
          MB[qh][qs][nf][4 * lg + j][lr] = o[qs][nf][j];
      if (lg == 0) {
        ML[qh][qs][0][lr] = m_[qs];
        ML[qh][qs][1][lr] = l_[qs];
      }
    }
  }
  __syncthreads();
  if (!par) {
    int b = bh >> 4, h = bh & 15;
#pragma unroll
    for (int qs = 0; qs < 4; ++qs) {
      float m1 = ML[qh][qs][0][lr];
      float l1 = ML[qh][qs][1][lr];
      float ms = fmaxf(m_[qs], m1);
      float a0 = exp2f((m_[qs] - ms) * SC), a1 = exp2f((m1 - ms) * SC);
      float inv = 1.0f / (a0 * l_[qs] + a1 * l1);
#pragma unroll
      for (int j = 0; j < 4; ++j) {
        float c0 = __shfl(a0 * inv, 4 * lg + j);
        float c1 = __shfl(a1 * inv, 4 * lg + j);
#pragma unroll
        for (int nf = 0; nf < 4; ++nf) {
          float o1 = MB[qh][qs][nf][4 * lg + j][lr];
          int q = q0 + qh * 64 + 16 * qs + 4 * lg + j;
          out[(b * 2048 + q) * 1024 + h * 64 + nf * 16 + lr] =
              c0 * o[qs][nf][j] + c1 * o1;
        }
      }
    }
  }
}

extern "C" void kernel_launch(void* const* d_in, const int* in_sizes, int n_in,
                              void* d_out, int out_size, void* d_ws, size_t ws_size,
                              hipStream_t stream) {
  const float* x = (const float*)d_in[0];
  const float* Wq = (const float*)d_in[1];
  const float* Wv = (const float*)d_in[2];
  const float* cosT = (const float*)d_in[3];
  const float* sinT = (const float*)d_in[4];
  float* out = (float*)d_out;

  unsigned short* xb = (unsigned short*)d_ws;        // 4M shorts
  unsigned short* wqb = xb + 4 * 1024 * 1024;        // 1M
  unsigned short* wvb = wqb + 1024 * 1024;           // 1M
  unsigned short* Kfb = wvb + 1024 * 1024;           // 4M (frag-layout RoPE'd Q==K)
  unsigned short* Vfb = Kfb + 4 * 1024 * 1024;       // 4M (frag-layout V)

  convert_all<<<6144, 256, 0, stream>>>(x, Wq, Wv, xb, wqb, wvb);
  qv_gemm<<<512, 256, 0, stream>>>(xb, wqb, wvb, cosT, sinT, Kfb, Vfb);
  attn<<<512, 256, 0, stream>>>(Kfb, Vfb, out);
}

// Round 11
// 69.529 us; speedup vs baseline: 1.3230x; 1.3230x over previous
//
#include <hip/hip_runtime.h>

// B=2, S=2048, D=1024, H=16, HD=64. K == Q (xk = x@Wq.T, same RoPE).
// Pipeline: fused f32->bf16 convert -> merged GEMM (R7 mapping):
//   [x@Wq.T + RoPE -> Kf frag-layout], [x@Wv.T -> Vf frag-layout]
// -> flash attention, no LDS/barriers in main loop, frag loads coalesced.
// R11: exact R7 restore (32 q-rows/wave, 96 VGPR, grid 1024, no setprio);
//   single delta: qt dispatch order interleaves heavy/light (31,0,30,1,...)
//   so the tail keeps mixed blocks resident.

typedef float f32x4 __attribute__((ext_vector_type(4)));
typedef short s16x8 __attribute__((ext_vector_type(8)));

__device__ inline unsigned short f2bf(float f) {
  union { float f; unsigned u; } v; v.f = f;
  unsigned r = v.u + 0x7FFFu + ((v.u >> 16) & 1u);
  return (unsigned short)(r >> 16);
}

__device__ inline void gload16(const unsigned short* g, unsigned short* l) {
  __builtin_amdgcn_global_load_lds(
      (const __attribute__((address_space(1))) unsigned int*)g,
      (__attribute__((address_space(3))) unsigned int*)l, 16, 0, 0);
}

__global__ __launch_bounds__(256) void convert_all(
    const float* __restrict__ x, const float* __restrict__ wq,
    const float* __restrict__ wv, unsigned short* __restrict__ xb,
    unsigned short* __restrict__ wqb, unsigned short* __restrict__ wvb) {
  int i = blockIdx.x * 256 + threadIdx.x;
  const float* src; unsigned short* dst; int off;
  if (i < 1048576) { src = x; dst = xb; off = i; }
  else if (i < 1310720) { src = wq; dst = wqb; off = i - 1048576; }
  else { src = wv; dst = wvb; off = i - 1310720; }
  float4 v = ((const float4*)src)[off];
  ushort4 o;
  o.x = f2bf(v.x); o.y = f2bf(v.y); o.z = f2bf(v.z); o.w = f2bf(v.w);
  ((ushort4*)dst)[off] = o;
}

// Merged GEMM: grid 512. Blocks [0,256) -> Q-proj (+RoPE) -> Kf.
// Blocks [256,512) -> V-proj -> Vf.  M=4096 N=1024 K=1024, bf16, f32 acc.
__global__ __launch_bounds__(256, 2) void qv_gemm(
    const unsigned short* __restrict__ A, const unsigned short* __restrict__ Wq,
    const unsigned short* __restrict__ Wv, const float* __restrict__ cosT,
    const float* __restrict__ sinT, unsigned short* __restrict__ Kf,
    unsigned short* __restrict__ Vf) {
  __shared__ unsigned short GS[2][2][128][64];  // [buf][A/B][row][col] 64KB
  int tid = threadIdx.x;
  int isq = blockIdx.x < 256;
  int b256 = blockIdx.x & 255;
  int bm = b256 & 31, bn = b256 >> 5;
  int w = tid >> 6, lane = tid & 63, lr = lane & 15, lg = lane >> 4;
  int wm = w >> 1, wn = w & 1;
  int l8 = lane >> 3, l7 = lane & 7;
  f32x4 acc[4][4] = {};

  const unsigned short* Wp = isq ? Wq : Wv;
  const unsigned short* srcbase =
      (w < 2) ? (A + bm * 128 * 1024) : (Wp + bn * 128 * 1024);
  int ab = w >> 1;

  auto stage = [&](int step) {
    int buf = step & 1, kt = step * 64;
#pragma unroll
    for (int i = 0; i < 8; ++i) {
      int rgrp = (w & 1) * 8 + i;
      int u = rgrp * 8 + l8;
      int ch = l7 ^ (u & 7);
      gload16(srcbase + u * 1024 + kt + ch * 8,
              (unsigned short*)&GS[buf][ab][rgrp * 8][0]);
    }
  };

  stage(0);
  for (int step = 0; step < 16; ++step) {
    int buf = step & 1;
    asm volatile("s_waitcnt vmcnt(0)" ::: "memory");
    __syncthreads();
    if (step + 1 < 16) stage(step + 1);
    s16x8 af[4][2], bfr[4][2];
#pragma unroll
    for (int mf = 0; mf < 4; ++mf)
#pragma unroll
      for (int kk = 0; kk < 2; ++kk)
        af[mf][kk] = *(const s16x8*)
            &GS[buf][0][wm * 64 + mf * 16 + lr][((kk * 4 + lg) ^ (lr & 7)) * 8];
#pragma unroll
    for (int nf = 0; nf < 4; ++nf)
#pragma unroll
      for (int kk = 0; kk < 2; ++kk)
        bfr[nf][kk] = *(const s16x8*)
            &GS[buf][1][wn * 64 + nf * 16 + lr][((kk * 4 + lg) ^ (lr & 7)) * 8];
#pragma unroll
    for (int mf = 0; mf < 4; ++mf)
#pragma unroll
      for (int nf = 0; nf < 4; ++nf)
#pragma unroll
        for (int kk = 0; kk < 2; ++kk)
          acc[mf][nf] = __builtin_amdgcn_mfma_f32_16x16x32_bf16(
              af[mf][kk], bfr[nf][kk], acc[mf][nf], 0, 0, 0);
  }

  int mBase = bm * 128 + wm * 64;
  int nBase = bn * 128 + wn * 64;
  if (isq) {
    // RoPE, then per-wave LDS transpose -> coalesced dwordx4 Kf stores.
    __syncthreads();
    unsigned short* Lw = &GS[0][0][0][0] + w * (64 * 72);
    int bq = mBase >> 11;
    int sbase = mBase & 2047;
    int kt = sbase >> 6;
    int h = (nBase >> 6);
    int bh = bq * 16 + h;
#pragma unroll
    for (int mf = 0; mf < 4; ++mf)
#pragma unroll
      for (int j = 0; j < 4; ++j) {
        int sp = mf * 16 + 4 * lg + j;
        int s = sbase + sp;
#pragma unroll
        for (int nf = 0; nf < 4; ++nf) {
          int hd = nf * 16 + lr;
          float self = acc[mf][nf][j];
          float part = (nf < 2) ? -acc[mf][nf + 2][j] : acc[mf][nf - 2][j];
          float val = self * cosT[s * 64 + hd] + part * sinT[s * 64 + hd];
          Lw[sp * 72 + hd] = f2bf(val);
        }
      }
    asm volatile("s_waitcnt lgkmcnt(0)" ::: "memory");
    __builtin_amdgcn_sched_barrier(0);
    unsigned short* KfT = Kf + (size_t)(bh * 32 + kt) * 4096;
#pragma unroll
    for (int i = 0; i < 8; ++i) {
      int kk = i & 1, nfk = i >> 1;
      int lg2 = lane >> 4, lr2 = lane & 15;
      int sp = ((nfk >> 1) << 5) | ((lr2 >> 2) << 3) | ((nfk & 1) << 2) |
               (lr2 & 3);
      int c = kk * 4 + lg2;
      s16x8 vch = *(const s16x8*)&Lw[sp * 72 + c * 8];
      *(s16x8*)&KfT[(i * 64 + lane) * 8] = vch;
    }
  } else {
#pragma unroll
    for (int mf = 0; mf < 4; ++mf) {
      int m0 = mBase + mf * 16 + 4 * lg;
      int b = m0 >> 11, s0 = m0 & 2047;
      int kt = s0 >> 6, w0 = s0 & 63;
      int kkv = w0 >> 5, lg2 = (w0 >> 3) & 3, e0 = w0 & 7;
#pragma unroll
      for (int nf = 0; nf < 4; ++nf) {
        int col = nBase + nf * 16 + lr;
        int h = col >> 6;
        int bh = b * 16 + h;
        ushort4 pk;
        pk.x = f2bf(acc[mf][nf][0]); pk.y = f2bf(acc[mf][nf][1]);
        pk.z = f2bf(acc[mf][nf][2]); pk.w = f2bf(acc[mf][nf][3]);
        int idx2 = (((((bh * 32 + kt) * 4 + nf) * 2 + kkv) * 64) +
                    lg2 * 16 + lr) * 8 + e0;
        *(ushort4*)&Vf[idx2] = pk;
      }
    }
  }
}

// Flash attention: no LDS / no barriers in main loop. grid 1024,
// fid -> XCD-chunked bh; qt interleaved heavy/light (31,0,30,1,...).
// 4 waves = (q-half, k-parity). Frag loads are coalesced 1KB dwordx4
// from Kf/Vf. Pairwise merge via LDS.
__global__ __launch_bounds__(256, 2) void attn(
    const unsigned short* __restrict__ Kf,  // frag layout
    const unsigned short* __restrict__ Vf,  // frag layout
    float* __restrict__ out) {              // [2][2048][1024]
  __shared__ float MB[2][2][4][16][17];
  __shared__ float ML[2][2][2][16];
  const float SC = 0.125f * 1.44269504088896f;  // scale * log2(e)
  const float THR = 44.0f;                      // ~= 8 / SC
  int tid = threadIdx.x;
  int fid = blockIdx.x;
  int bh = 4 * (fid & 7) + ((fid >> 3) & 3);
  int hi = fid >> 5;                            // 0..31
  int qt = (hi & 1) ? (hi >> 1) : (31 - (hi >> 1));  // 31,0,30,1,...,16,15
  int w = tid >> 6, lane = tid & 63, lr = lane & 15, lg = lane >> 4;
  int q0 = qt * 64, qh = w >> 1, par = w & 1;

  const unsigned short* KfB = Kf + (size_t)bh * 32 * 4096;
  const unsigned short* VfB = Vf + (size_t)bh * 32 * 4096;

  // aq (B-operand) gathered from Kf once.
  s16x8 aq[2][2];
#pragma unroll
  for (int qs = 0; qs < 2; ++qs) {
    int qr = q0 + qh * 32 + 16 * qs + lr;
    int ktq = qr >> 6, w64 = qr & 63;
    int nfq = ((w64 >> 5) << 1) | ((w64 >> 2) & 1);
    int r31 = w64 & 31;
    int lr2 = ((r31 >> 3) << 2) | (r31 & 3);
#pragma unroll
    for (int kk = 0; kk < 2; ++kk)
      aq[qs][kk] = *(const s16x8*)
          &KfB[((((ktq * 4 + nfq) * 2 + kk) * 64) + lg * 16 + lr2) * 8];
  }

  f32x4 o[2][4] = {};
  float m_[2] = {-1e30f, -1e30f}, l_[2] = {0.f, 0.f};

  s16x8 kf[4][2], vf[4][2];
  auto loadK = [&](int kt_) {
#pragma unroll
    for (int nf = 0; nf < 4; ++nf)
#pragma unroll
      for (int kk = 0; kk < 2; ++kk)
        kf[nf][kk] = *(const s16x8*)
            &KfB[(((kt_ * 4 + nf) * 2 + kk) * 64 + lane) * 8];
  };
  auto loadV = [&](int kt_) {
#pragma unroll
    for (int nf = 0; nf < 4; ++nf)
#pragma unroll
      for (int kk = 0; kk < 2; ++kk)
        vf[nf][kk] = *(const s16x8*)
            &VfB[(((kt_ * 4 + nf) * 2 + kk) * 64 + lane) * 8];
  };

  int kt = par;
  bool active = kt <= qt;
  if (active) { loadK(kt); loadV(kt); }
  while (active) {
    // QK^T (swapped): sa[qs][nf][j] = S[kcol=kt*64+8lg+j+off(nf)][q0+qh*32+16qs+lr]
    f32x4 sa[2][4];
#pragma unroll
    for (int qs = 0; qs < 2; ++qs)
#pragma unroll
      for (int nf = 0; nf < 4; ++nf) sa[qs][nf] = (f32x4){0.f, 0.f, 0.f, 0.f};
#pragma unroll
    for (int kk = 0; kk < 2; ++kk)
#pragma unroll
      for (int nf = 0; nf < 4; ++nf)
#pragma unroll
        for (int qs = 0; qs < 2; ++qs)
          sa[qs][nf] = __builtin_amdgcn_mfma_f32_16x16x32_bf16(
              kf[nf][kk], aq[qs][kk], sa[qs][nf], 0, 0, 0);

    int ktn = kt + 2;
    bool more = ktn <= qt;
    if (more) loadK(ktn);  // pipelined: lands during softmax+PV

    if (kt == qt) {
#pragma unroll
      for (int qs = 0; qs < 2; ++qs) {
        int qglob = q0 + qh * 32 + 16 * qs + lr;
#pragma unroll
        for (int nf = 0; nf < 4; ++nf) {
          int kc = kt * 64 + 8 * lg + 4 * (nf & 1) + 32 * (nf >> 1);
#pragma unroll
          for (int j = 0; j < 4; ++j)
            if (kc + j > qglob) sa[qs][nf][j] = -3e38f;
        }
      }
    }
    float tm[2];
    float worst = -3e38f;
#pragma unroll
    for (int qs = 0; qs < 2; ++qs) {
      float t = sa[qs][0][0];
#pragma unroll
      for (int nf = 0; nf < 4; ++nf)
#pragma unroll
        for (int j = 0; j < 4; ++j) t = fmaxf(t, sa[qs][nf][j]);
      tm[qs] = t;
      worst = fmaxf(worst, t - m_[qs]);
    }
    if (!__all(worst <= THR)) {  // rare after first tile
#pragma unroll
      for (int qs = 0; qs < 2; ++qs) {
        float rm = fmaxf(tm[qs], __shfl_xor(tm[qs], 16));
        rm = fmaxf(rm, __shfl_xor(rm, 32));
        float mn = fmaxf(m_[qs], rm);
        float alpha = exp2f((m_[qs] - mn) * SC);
        m_[qs] = mn; l_[qs] *= alpha;
#pragma unroll
        for (int j = 0; j < 4; ++j) {
          float aj = __shfl(alpha, 4 * lg + j);
#pragma unroll
          for (int nf = 0; nf < 4; ++nf) o[qs][nf][j] *= aj;
        }
      }
    }
    unsigned cpk[2][8];
#pragma unroll
    for (int qs = 0; qs < 2; ++qs) {
      float msc = m_[qs] * SC;
#pragma unroll
      for (int nf = 0; nf < 4; ++nf) {
        float p0 = exp2f(fmaf(sa[qs][nf][0], SC, -msc));
        float p1 = exp2f(fmaf(sa[qs][nf][1], SC, -msc));
        float p2 = exp2f(fmaf(sa[qs][nf][2], SC, -msc));
        float p3 = exp2f(fmaf(sa[qs][nf][3], SC, -msc));
        l_[qs] += (p0 + p1) + (p2 + p3);
        unsigned r0, r1;
        asm("v_cvt_pk_bf16_f32 %0, %1, %2" : "=v"(r0) : "v"(p0), "v"(p1));
        asm("v_cvt_pk_bf16_f32 %0, %1, %2" : "=v"(r1) : "v"(p2), "v"(p3));
        cpk[qs][nf * 2] = r0; cpk[qs][nf * 2 + 1] = r1;
      }
    }
    s16x8 pav[2][2];
#pragma unroll
    for (int qs = 0; qs < 2; ++qs)
#pragma unroll
      for (int kk = 0; kk < 2; ++kk) {
        union { unsigned u[4]; s16x8 v; } pa;
        pa.u[0] = cpk[qs][4 * kk + 0]; pa.u[1] = cpk[qs][4 * kk + 1];
        pa.u[2] = cpk[qs][4 * kk + 2]; pa.u[3] = cpk[qs][4 * kk + 3];
        pav[qs][kk] = pa.v;
      }
#pragma unroll
    for (int kk = 0; kk < 2; ++kk)
#pragma unroll
      for (int nf = 0; nf < 4; ++nf)
#pragma unroll
        for (int qs = 0; qs < 2; ++qs)
          o[qs][nf] = __builtin_amdgcn_mfma_f32_16x16x32_bf16(
              pav[qs][kk], vf[nf][kk], o[qs][nf], 0, 0, 0);
    if (more) loadV(ktn);  // lands during next QK^T+softmax
    kt = ktn; active = more;
  }

  // pairwise merge: waves (qh,0) and (qh,1) share q-rows; odd writes, even merges
#pragma unroll
  for (int qs = 0; qs < 2; ++qs) {
    float t = l_[qs];
    t += __shfl_xor(t, 16); t += __shfl_xor(t, 32);
    l_[qs] = t;
  }
  if (par) {
#pragma unroll
    for (int qs = 0; qs < 2; ++qs) {
#pragma unroll
      for (int nf = 0; nf < 4; ++nf)
#pragma unroll
        for (int j = 0; j < 4; ++j)
          MB[qh][qs][nf][4 * lg + j][lr] = o[qs][nf][j];
      if (lg == 0) {
        ML[qh][qs][0][lr] = m_[qs];
        ML[qh][qs][1][lr] = l_[qs];
      }
    }
  }
  __syncthreads();
  if (!par) {
    int b = bh >> 4, h = bh & 15;
#pragma unroll
    for (int qs = 0; qs < 2; ++qs) {
      float m1 = ML[qh][qs][0][lr];
      float l1 = ML[qh][qs][1][lr];
      float ms = fmaxf(m_[qs], m1);
      float a0 = exp2f((m_[qs] - ms) * SC), a1 = exp2f((m1 - ms) * SC);
      float inv = 1.0f / (a0 * l_[qs] + a1 * l1);
#pragma unroll
      for (int j = 0; j < 4; ++j) {
        float c0 = __shfl(a0 * inv, 4 * lg + j);
        float c1 = __shfl(a1 * inv, 4 * lg + j);
#pragma unroll
        for (int nf = 0; nf < 4; ++nf) {
          float o1 = MB[qh][qs][nf][4 * lg + j][lr];
          int q = q0 + qh * 32 + 16 * qs + 4 * lg + j;
          out[(b * 2048 + q) * 1024 + h * 64 + nf * 16 + lr] =
              c0 * o[qs][nf][j] + c1 * o1;
        }
      }
    }
  }
}

extern "C" void kernel_launch(void* const* d_in, const int* in_sizes, int n_in,
                              void* d_out, int out_size, void* d_ws, size_t ws_size,
                              hipStream_t stream) {
  const float* x = (const float*)d_in[0];
  const float* Wq = (const float*)d_in[1];
  const float* Wv = (const float*)d_in[2];
  const float* cosT = (const float*)d_in[3];
  const float* sinT = (const float*)d_in[4];
  float* out = (float*)d_out;

  unsigned short* xb = (unsigned short*)d_ws;        // 4M shorts
  unsigned short* wqb = xb + 4 * 1024 * 1024;        // 1M
  unsigned short* wvb = wqb + 1024 * 1024;           // 1M
  unsigned short* Kfb = wvb + 1024 * 1024;           // 4M (frag-layout RoPE'd Q==K)
  unsigned short* Vfb = Kfb + 4 * 1024 * 1024;       // 4M (frag-layout V)

  convert_all<<<6144, 256, 0, stream>>>(x, Wq, Wv, xb, wqb, wvb);
  qv_gemm<<<512, 256, 0, stream>>>(xb, wqb, wvb, cosT, sinT, Kfb, Vfb);
  attn<<<1024, 256, 0, stream>>>(Kfb, Vfb, out);
}

// Round 12
// 68.730 us; speedup vs baseline: 1.3384x; 1.0116x over previous
//
#include <hip/hip_runtime.h>

// B=2, S=2048, D=1024, H=16, HD=64. K == Q (xk = x@Wq.T, same RoPE).
// Pipeline: fused f32->bf16 convert -> merged GEMM (R7 mapping):
//   [x@Wq.T + RoPE -> Kf frag-layout], [x@Wv.T -> Vf frag-layout]
// -> flash attention, no LDS/barriers in main loop, frag loads coalesced.
// R12: per-CU-balanced qt map. All 1024 blocks are co-resident (4/CU);
//   CU j gets hi in {j>>2, j>>2+8, +16, +24} (round-robin model), so
//   qt = {31-h, 16+h, 15-h, h}[g] (h=hi&7, g=hi>>3) makes every CU's
//   visit sum exactly 66. bh map unchanged (4 blocks/CU share one head).

typedef float f32x4 __attribute__((ext_vector_type(4)));
typedef short s16x8 __attribute__((ext_vector_type(8)));

__device__ inline unsigned short f2bf(float f) {
  union { float f; unsigned u; } v; v.f = f;
  unsigned r = v.u + 0x7FFFu + ((v.u >> 16) & 1u);
  return (unsigned short)(r >> 16);
}

__device__ inline void gload16(const unsigned short* g, unsigned short* l) {
  __builtin_amdgcn_global_load_lds(
      (const __attribute__((address_space(1))) unsigned int*)g,
      (__attribute__((address_space(3))) unsigned int*)l, 16, 0, 0);
}

__global__ __launch_bounds__(256) void convert_all(
    const float* __restrict__ x, const float* __restrict__ wq,
    const float* __restrict__ wv, unsigned short* __restrict__ xb,
    unsigned short* __restrict__ wqb, unsigned short* __restrict__ wvb) {
  int i = blockIdx.x * 256 + threadIdx.x;
  const float* src; unsigned short* dst; int off;
  if (i < 1048576) { src = x; dst = xb; off = i; }
  else if (i < 1310720) { src = wq; dst = wqb; off = i - 1048576; }
  else { src = wv; dst = wvb; off = i - 1310720; }
  float4 v = ((const float4*)src)[off];
  ushort4 o;
  o.x = f2bf(v.x); o.y = f2bf(v.y); o.z = f2bf(v.z); o.w = f2bf(v.w);
  ((ushort4*)dst)[off] = o;
}

// Merged GEMM: grid 512. Blocks [0,256) -> Q-proj (+RoPE) -> Kf.
// Blocks [256,512) -> V-proj -> Vf.  M=4096 N=1024 K=1024, bf16, f32 acc.
__global__ __launch_bounds__(256, 2) void qv_gemm(
    const unsigned short* __restrict__ A, const unsigned short* __restrict__ Wq,
    const unsigned short* __restrict__ Wv, const float* __restrict__ cosT,
    const float* __restrict__ sinT, unsigned short* __restrict__ Kf,
    unsigned short* __restrict__ Vf) {
  __shared__ unsigned short GS[2][2][128][64];  // [buf][A/B][row][col] 64KB
  int tid = threadIdx.x;
  int isq = blockIdx.x < 256;
  int b256 = blockIdx.x & 255;
  int bm = b256 & 31, bn = b256 >> 5;
  int w = tid >> 6, lane = tid & 63, lr = lane & 15, lg = lane >> 4;
  int wm = w >> 1, wn = w & 1;
  int l8 = lane >> 3, l7 = lane & 7;
  f32x4 acc[4][4] = {};

  const unsigned short* Wp = isq ? Wq : Wv;
  const unsigned short* srcbase =
      (w < 2) ? (A + bm * 128 * 1024) : (Wp + bn * 128 * 1024);
  int ab = w >> 1;

  auto stage = [&](int step) {
    int buf = step & 1, kt = step * 64;
#pragma unroll
    for (int i = 0; i < 8; ++i) {
      int rgrp = (w & 1) * 8 + i;
      int u = rgrp * 8 + l8;
      int ch = l7 ^ (u & 7);
      gload16(srcbase + u * 1024 + kt + ch * 8,
              (unsigned short*)&GS[buf][ab][rgrp * 8][0]);
    }
  };

  stage(0);
  for (int step = 0; step < 16; ++step) {
    int buf = step & 1;
    asm volatile("s_waitcnt vmcnt(0)" ::: "memory");
    __syncthreads();
    if (step + 1 < 16) stage(step + 1);
    s16x8 af[4][2], bfr[4][2];
#pragma unroll
    for (int mf = 0; mf < 4; ++mf)
#pragma unroll
      for (int kk = 0; kk < 2; ++kk)
        af[mf][kk] = *(const s16x8*)
            &GS[buf][0][wm * 64 + mf * 16 + lr][((kk * 4 + lg) ^ (lr & 7)) * 8];
#pragma unroll
    for (int nf = 0; nf < 4; ++nf)
#pragma unroll
      for (int kk = 0; kk < 2; ++kk)
        bfr[nf][kk] = *(const s16x8*)
            &GS[buf][1][wn * 64 + nf * 16 + lr][((kk * 4 + lg) ^ (lr & 7)) * 8];
#pragma unroll
    for (int mf = 0; mf < 4; ++mf)
#pragma unroll
      for (int nf = 0; nf < 4; ++nf)
#pragma unroll
        for (int kk = 0; kk < 2; ++kk)
          acc[mf][nf] = __builtin_amdgcn_mfma_f32_16x16x32_bf16(
              af[mf][kk], bfr[nf][kk], acc[mf][nf], 0, 0, 0);
  }

  int mBase = bm * 128 + wm * 64;
  int nBase = bn * 128 + wn * 64;
  if (isq) {
    // RoPE, then per-wave LDS transpose -> coalesced dwordx4 Kf stores.
    __syncthreads();
    unsigned short* Lw = &GS[0][0][0][0] + w * (64 * 72);
    int bq = mBase >> 11;
    int sbase = mBase & 2047;
    int kt = sbase >> 6;
    int h = (nBase >> 6);
    int bh = bq * 16 + h;
#pragma unroll
    for (int mf = 0; mf < 4; ++mf)
#pragma unroll
      for (int j = 0; j < 4; ++j) {
        int sp = mf * 16 + 4 * lg + j;
        int s = sbase + sp;
#pragma unroll
        for (int nf = 0; nf < 4; ++nf) {
          int hd = nf * 16 + lr;
          float self = acc[mf][nf][j];
          float part = (nf < 2) ? -acc[mf][nf + 2][j] : acc[mf][nf - 2][j];
          float val = self * cosT[s * 64 + hd] + part * sinT[s * 64 + hd];
          Lw[sp * 72 + hd] = f2bf(val);
        }
      }
    asm volatile("s_waitcnt lgkmcnt(0)" ::: "memory");
    __builtin_amdgcn_sched_barrier(0);
    unsigned short* KfT = Kf + (size_t)(bh * 32 + kt) * 4096;
#pragma unroll
    for (int i = 0; i < 8; ++i) {
      int kk = i & 1, nfk = i >> 1;
      int lg2 = lane >> 4, lr2 = lane & 15;
      int sp = ((nfk >> 1) << 5) | ((lr2 >> 2) << 3) | ((nfk & 1) << 2) |
               (lr2 & 3);
      int c = kk * 4 + lg2;
      s16x8 vch = *(const s16x8*)&Lw[sp * 72 + c * 8];
      *(s16x8*)&KfT[(i * 64 + lane) * 8] = vch;
    }
  } else {
#pragma unroll
    for (int mf = 0; mf < 4; ++mf) {
      int m0 = mBase + mf * 16 + 4 * lg;
      int b = m0 >> 11, s0 = m0 & 2047;
      int kt = s0 >> 6, w0 = s0 & 63;
      int kkv = w0 >> 5, lg2 = (w0 >> 3) & 3, e0 = w0 & 7;
#pragma unroll
      for (int nf = 0; nf < 4; ++nf) {
        int col = nBase + nf * 16 + lr;
        int h = col >> 6;
        int bh = b * 16 + h;
        ushort4 pk;
        pk.x = f2bf(acc[mf][nf][0]); pk.y = f2bf(acc[mf][nf][1]);
        pk.z = f2bf(acc[mf][nf][2]); pk.w = f2bf(acc[mf][nf][3]);
        int idx2 = (((((bh * 32 + kt) * 4 + nf) * 2 + kkv) * 64) +
                    lg2 * 16 + lr) * 8 + e0;
        *(ushort4*)&Vf[idx2] = pk;
      }
    }
  }
}

// Flash attention: no LDS / no barriers in main loop. grid 1024,
// fid -> XCD-chunked bh; per-CU-balanced qt map (sum 62 per CU under
// round-robin placement). 4 waves = (q-half, k-parity). Frag loads are
// coalesced 1KB dwordx4 from Kf/Vf. Pairwise merge via LDS.
__global__ __launch_bounds__(256, 2) void attn(
    const unsigned short* __restrict__ Kf,  // frag layout
    const unsigned short* __restrict__ Vf,  // frag layout
    float* __restrict__ out) {              // [2][2048][1024]
  __shared__ float MB[2][2][4][16][17];
  __shared__ float ML[2][2][2][16];
  const float SC = 0.125f * 1.44269504088896f;  // scale * log2(e)
  const float THR = 44.0f;                      // ~= 8 / SC
  int tid = threadIdx.x;
  int fid = blockIdx.x;
  int bh = 4 * (fid & 7) + ((fid >> 3) & 3);
  int hi = fid >> 5;                        // 0..31
  int hq = hi & 7, g = hi >> 3;             // CU j sees one hi per g
  int qt = (g == 0) ? (31 - hq) : (g == 1) ? (16 + hq)
         : (g == 2) ? (15 - hq) : hq;       // per-CU qt sum = 62 (balanced)
  int w = tid >> 6, lane = tid & 63, lr = lane & 15, lg = lane >> 4;
  int q0 = qt * 64, qh = w >> 1, par = w & 1;

  const unsigned short* KfB = Kf + (size_t)bh * 32 * 4096;
  const unsigned short* VfB = Vf + (size_t)bh * 32 * 4096;

  // aq (B-operand) gathered from Kf once.
  s16x8 aq[2][2];
#pragma unroll
  for (int qs = 0; qs < 2; ++qs) {
    int qr = q0 + qh * 32 + 16 * qs + lr;
    int ktq = qr >> 6, w64 = qr & 63;
    int nfq = ((w64 >> 5) << 1) | ((w64 >> 2) & 1);
    int r31 = w64 & 31;
    int lr2 = ((r31 >> 3) << 2) | (r31 & 3);
#pragma unroll
    for (int kk = 0; kk < 2; ++kk)
      aq[qs][kk] = *(const s16x8*)
          &KfB[((((ktq * 4 + nfq) * 2 + kk) * 64) + lg * 16 + lr2) * 8];
  }

  f32x4 o[2][4] = {};
  float m_[2] = {-1e30f, -1e30f}, l_[2] = {0.f, 0.f};

  s16x8 kf[4][2], vf[4][2];
  auto loadK = [&](int kt_) {
#pragma unroll
    for (int nf = 0; nf < 4; ++nf)
#pragma unroll
      for (int kk = 0; kk < 2; ++kk)
        kf[nf][kk] = *(const s16x8*)
            &KfB[(((kt_ * 4 + nf) * 2 + kk) * 64 + lane) * 8];
  };
  auto loadV = [&](int kt_) {
#pragma unroll
    for (int nf = 0; nf < 4; ++nf)
#pragma unroll
      for (int kk = 0; kk < 2; ++kk)
        vf[nf][kk] = *(const s16x8*)
            &VfB[(((kt_ * 4 + nf) * 2 + kk) * 64 + lane) * 8];
  };

  int kt = par;
  bool active = kt <= qt;
  if (active) { loadK(kt); loadV(kt); }
  while (active) {
    // QK^T (swapped): sa[qs][nf][j] = S[kcol=kt*64+8lg+j+off(nf)][q0+qh*32+16qs+lr]
    f32x4 sa[2][4];
#pragma unroll
    for (int qs = 0; qs < 2; ++qs)
#pragma unroll
      for (int nf = 0; nf < 4; ++nf) sa[qs][nf] = (f32x4){0.f, 0.f, 0.f, 0.f};
#pragma unroll
    for (int kk = 0; kk < 2; ++kk)
#pragma unroll
      for (int nf = 0; nf < 4; ++nf)
#pragma unroll
        for (int qs = 0; qs < 2; ++qs)
          sa[qs][nf] = __builtin_amdgcn_mfma_f32_16x16x32_bf16(
              kf[nf][kk], aq[qs][kk], sa[qs][nf], 0, 0, 0);

    int ktn = kt + 2;
    bool more = ktn <= qt;
    if (more) loadK(ktn);  // pipelined: lands during softmax+PV

    if (kt == qt) {
#pragma unroll
      for (int qs = 0; qs < 2; ++qs) {
        int qglob = q0 + qh * 32 + 16 * qs + lr;
#pragma unroll
        for (int nf = 0; nf < 4; ++nf) {
          int kc = kt * 64 + 8 * lg + 4 * (nf & 1) + 32 * (nf >> 1);
#pragma unroll
          for (int j = 0; j < 4; ++j)
            if (kc + j > qglob) sa[qs][nf][j] = -3e38f;
        }
      }
    }
    float tm[2];
    float worst = -3e38f;
#pragma unroll
    for (int qs = 0; qs < 2; ++qs) {
      float t = sa[qs][0][0];
#pragma unroll
      for (int nf = 0; nf < 4; ++nf)
#pragma unroll
        for (int j = 0; j < 4; ++j) t = fmaxf(t, sa[qs][nf][j]);
      tm[qs] = t;
      worst = fmaxf(worst, t - m_[qs]);
    }
    if (!__all(worst <= THR)) {  // rare after first tile
#pragma unroll
      for (int qs = 0; qs < 2; ++qs) {
        float rm = fmaxf(tm[qs], __shfl_xor(tm[qs], 16));
        rm = fmaxf(rm, __shfl_xor(rm, 32));
        float mn = fmaxf(m_[qs], rm);
        float alpha = exp2f((m_[qs] - mn) * SC);
        m_[qs] = mn; l_[qs] *= alpha;
#pragma unroll
        for (int j = 0; j < 4; ++j) {
          float aj = __shfl(alpha, 4 * lg + j);
#pragma unroll
          for (int nf = 0; nf < 4; ++nf) o[qs][nf][j] *= aj;
        }
      }
    }
    unsigned cpk[2][8];
#pragma unroll
    for (int qs = 0; qs < 2; ++qs) {
      float msc = m_[qs] * SC;
#pragma unroll
      for (int nf = 0; nf < 4; ++nf) {
        float p0 = exp2f(fmaf(sa[qs][nf][0], SC, -msc));
        float p1 = exp2f(fmaf(sa[qs][nf][1], SC, -msc));
        float p2 = exp2f(fmaf(sa[qs][nf][2], SC, -msc));
        float p3 = exp2f(fmaf(sa[qs][nf][3], SC, -msc));
        l_[qs] += (p0 + p1) + (p2 + p3);
        unsigned r0, r1;
        asm("v_cvt_pk_bf16_f32 %0, %1, %2" : "=v"(r0) : "v"(p0), "v"(p1));
        asm("v_cvt_pk_bf16_f32 %0, %1, %2" : "=v"(r1) : "v"(p2), "v"(p3));
        cpk[qs][nf * 2] = r0; cpk[qs][nf * 2 + 1] = r1;
      }
    }
    s16x8 pav[2][2];
#pragma unroll
    for (int qs = 0; qs < 2; ++qs)
#pragma unroll
      for (int kk = 0; kk < 2; ++kk) {
        union { unsigned u[4]; s16x8 v; } pa;
        pa.u[0] = cpk[qs][4 * kk + 0]; pa.u[1] = cpk[qs][4 * kk + 1];
        pa.u[2] = cpk[qs][4 * kk + 2]; pa.u[3] = cpk[qs][4 * kk + 3];
        pav[qs][kk] = pa.v;
      }
#pragma unroll
    for (int kk = 0; kk < 2; ++kk)
#pragma unroll
      for (int nf = 0; nf < 4; ++nf)
#pragma unroll
        for (int qs = 0; qs < 2; ++qs)
          o[qs][nf] = __builtin_amdgcn_mfma_f32_16x16x32_bf16(
              pav[qs][kk], vf[nf][kk], o[qs][nf], 0, 0, 0);
    if (more) loadV(ktn);  // lands during next QK^T+softmax
    kt = ktn; active = more;
  }

  // pairwise merge: waves (qh,0) and (qh,1) share q-rows; odd writes, even merges
#pragma unroll
  for (int qs = 0; qs < 2; ++qs) {
    float t = l_[qs];
    t += __shfl_xor(t, 16); t += __shfl_xor(t, 32);
    l_[qs] = t;
  }
  if (par) {
#pragma unroll
    for (int qs = 0; qs < 2; ++qs) {
#pragma unroll
      for (int nf = 0; nf < 4; ++nf)
#pragma unroll
        for (int j = 0; j < 4; ++j)
          MB[qh][qs][nf][4 * lg + j][lr] = o[qs][nf][j];
      if (lg == 0) {
        ML[qh][qs][0][lr] = m_[qs];
        ML[qh][qs][1][lr] = l_[qs];
      }
    }
  }
  __syncthreads();
  if (!par) {
    int b = bh >> 4, h = bh & 15;
#pragma unroll
    for (int qs = 0; qs < 2; ++qs) {
      float m1 = ML[qh][qs][0][lr];
      float l1 = ML[qh][qs][1][lr];
      float ms = fmaxf(m_[qs], m1);
      float a0 = exp2f((m_[qs] - ms) * SC), a1 = exp2f((m1 - ms) * SC);
      float inv = 1.0f / (a0 * l_[qs] + a1 * l1);
#pragma unroll
      for (int j = 0; j < 4; ++j) {
        float c0 = __shfl(a0 * inv, 4 * lg + j);
        float c1 = __shfl(a1 * inv, 4 * lg + j);
#pragma unroll
        for (int nf = 0; nf < 4; ++nf) {
          float o1 = MB[qh][qs][nf][4 * lg + j][lr];
          int q = q0 + qh * 32 + 16 * qs + 4 * lg + j;
          out[(b * 2048 + q) * 1024 + h * 64 + nf * 16 + lr] =
              c0 * o[qs][nf][j] + c1 * o1;
        }
      }
    }
  }
}

extern "C" void kernel_launch(void* const* d_in, const int* in_sizes, int n_in,
                              void* d_out, int out_size, void* d_ws, size_t ws_size,
                              hipStream_t stream) {
  const float* x = (const float*)d_in[0];
  const float* Wq = (const float*)d_in[1];
  const float* Wv = (const float*)d_in[2];
  const float* cosT = (const float*)d_in[3];
  const float* sinT = (const float*)d_in[4];
  float* out = (float*)d_out;

  unsigned short* xb = (unsigned short*)d_ws;        // 4M shorts
  unsigned short* wqb = xb + 4 * 1024 * 1024;        // 1M
  unsigned short* wvb = wqb + 1024 * 1024;           // 1M
  unsigned short* Kfb = wvb + 1024 * 1024;           // 4M (frag-layout RoPE'd Q==K)
  unsigned short* Vfb = Kfb + 4 * 1024 * 1024;       // 4M (frag-layout V)

  convert_all<<<6144, 256, 0, stream>>>(x, Wq, Wv, xb, wqb, wvb);
  qv_gemm<<<512, 256, 0, stream>>>(xb, wqb, wvb, cosT, sinT, Kfb, Vfb);
  attn<<<1024, 256, 0, stream>>>(Kfb, Vfb, out);
}

// Round 13
// 68.375 us; speedup vs baseline: 1.3454x; 1.0052x over previous
//
#include <hip/hip_runtime.h>

// B=2, S=2048, D=1024, H=16, HD=64. K == Q (xk = x@Wq.T, same RoPE).
// Pipeline: fused f32->bf16 convert -> merged GEMM (R7 mapping):
//   [x@Wq.T + RoPE -> Kf frag-layout], [x@Wv.T -> Vf frag-layout]
// -> flash attention, no LDS/barriers in main loop, frag loads coalesced.
// R13: UNIFORM BLOCKS. grid 512; block handles q-tiles (31-pp) then (pp)
//   sequentially -> every block = exactly 33 k-tiles. Fixes the R12 tail
//   (Occupancy 16%: light blocks drained, heavy blocks ran at 1 wave/SIMD).

typedef float f32x4 __attribute__((ext_vector_type(4)));
typedef short s16x8 __attribute__((ext_vector_type(8)));

__device__ inline unsigned short f2bf(float f) {
  union { float f; unsigned u; } v; v.f = f;
  unsigned r = v.u + 0x7FFFu + ((v.u >> 16) & 1u);
  return (unsigned short)(r >> 16);
}

__device__ inline void gload16(const unsigned short* g, unsigned short* l) {
  __builtin_amdgcn_global_load_lds(
      (const __attribute__((address_space(1))) unsigned int*)g,
      (__attribute__((address_space(3))) unsigned int*)l, 16, 0, 0);
}

__global__ __launch_bounds__(256) void convert_all(
    const float* __restrict__ x, const float* __restrict__ wq,
    const float* __restrict__ wv, unsigned short* __restrict__ xb,
    unsigned short* __restrict__ wqb, unsigned short* __restrict__ wvb) {
  int i = blockIdx.x * 256 + threadIdx.x;
  const float* src; unsigned short* dst; int off;
  if (i < 1048576) { src = x; dst = xb; off = i; }
  else if (i < 1310720) { src = wq; dst = wqb; off = i - 1048576; }
  else { src = wv; dst = wvb; off = i - 1310720; }
  float4 v = ((const float4*)src)[off];
  ushort4 o;
  o.x = f2bf(v.x); o.y = f2bf(v.y); o.z = f2bf(v.z); o.w = f2bf(v.w);
  ((ushort4*)dst)[off] = o;
}

// Merged GEMM: grid 512. Blocks [0,256) -> Q-proj (+RoPE) -> Kf.
// Blocks [256,512) -> V-proj -> Vf.  M=4096 N=1024 K=1024, bf16, f32 acc.
__global__ __launch_bounds__(256, 2) void qv_gemm(
    const unsigned short* __restrict__ A, const unsigned short* __restrict__ Wq,
    const unsigned short* __restrict__ Wv, const float* __restrict__ cosT,
    const float* __restrict__ sinT, unsigned short* __restrict__ Kf,
    unsigned short* __restrict__ Vf) {
  __shared__ unsigned short GS[2][2][128][64];  // [buf][A/B][row][col] 64KB
  int tid = threadIdx.x;
  int isq = blockIdx.x < 256;
  int b256 = blockIdx.x & 255;
  int bm = b256 & 31, bn = b256 >> 5;
  int w = tid >> 6, lane = tid & 63, lr = lane & 15, lg = lane >> 4;
  int wm = w >> 1, wn = w & 1;
  int l8 = lane >> 3, l7 = lane & 7;
  f32x4 acc[4][4] = {};

  const unsigned short* Wp = isq ? Wq : Wv;
  const unsigned short* srcbase =
      (w < 2) ? (A + bm * 128 * 1024) : (Wp + bn * 128 * 1024);
  int ab = w >> 1;

  auto stage = [&](int step) {
    int buf = step & 1, kt = step * 64;
#pragma unroll
    for (int i = 0; i < 8; ++i) {
      int rgrp = (w & 1) * 8 + i;
      int u = rgrp * 8 + l8;
      int ch = l7 ^ (u & 7);
      gload16(srcbase + u * 1024 + kt + ch * 8,
              (unsigned short*)&GS[buf][ab][rgrp * 8][0]);
    }
  };

  stage(0);
  for (int step = 0; step < 16; ++step) {
    int buf = step & 1;
    asm volatile("s_waitcnt vmcnt(0)" ::: "memory");
    __syncthreads();
    if (step + 1 < 16) stage(step + 1);
    s16x8 af[4][2], bfr[4][2];
#pragma unroll
    for (int mf = 0; mf < 4; ++mf)
#pragma unroll
      for (int kk = 0; kk < 2; ++kk)
        af[mf][kk] = *(const s16x8*)
            &GS[buf][0][wm * 64 + mf * 16 + lr][((kk * 4 + lg) ^ (lr & 7)) * 8];
#pragma unroll
    for (int nf = 0; nf < 4; ++nf)
#pragma unroll
      for (int kk = 0; kk < 2; ++kk)
        bfr[nf][kk] = *(const s16x8*)
            &GS[buf][1][wn * 64 + nf * 16 + lr][((kk * 4 + lg) ^ (lr & 7)) * 8];
#pragma unroll
    for (int mf = 0; mf < 4; ++mf)
#pragma unroll
      for (int nf = 0; nf < 4; ++nf)
#pragma unroll
        for (int kk = 0; kk < 2; ++kk)
          acc[mf][nf] = __builtin_amdgcn_mfma_f32_16x16x32_bf16(
              af[mf][kk], bfr[nf][kk], acc[mf][nf], 0, 0, 0);
  }

  int mBase = bm * 128 + wm * 64;
  int nBase = bn * 128 + wn * 64;
  if (isq) {
    // RoPE, then per-wave LDS transpose -> coalesced dwordx4 Kf stores.
    __syncthreads();
    unsigned short* Lw = &GS[0][0][0][0] + w * (64 * 72);
    int bq = mBase >> 11;
    int sbase = mBase & 2047;
    int kt = sbase >> 6;
    int h = (nBase >> 6);
    int bh = bq * 16 + h;
#pragma unroll
    for (int mf = 0; mf < 4; ++mf)
#pragma unroll
      for (int j = 0; j < 4; ++j) {
        int sp = mf * 16 + 4 * lg + j;
        int s = sbase + sp;
#pragma unroll
        for (int nf = 0; nf < 4; ++nf) {
          int hd = nf * 16 + lr;
          float self = acc[mf][nf][j];
          float part = (nf < 2) ? -acc[mf][nf + 2][j] : acc[mf][nf - 2][j];
          float val = self * cosT[s * 64 + hd] + part * sinT[s * 64 + hd];
          Lw[sp * 72 + hd] = f2bf(val);
        }
      }
    asm volatile("s_waitcnt lgkmcnt(0)" ::: "memory");
    __builtin_amdgcn_sched_barrier(0);
    unsigned short* KfT = Kf + (size_t)(bh * 32 + kt) * 4096;
#pragma unroll
    for (int i = 0; i < 8; ++i) {
      int kk = i & 1, nfk = i >> 1;
      int lg2 = lane >> 4, lr2 = lane & 15;
      int sp = ((nfk >> 1) << 5) | ((lr2 >> 2) << 3) | ((nfk & 1) << 2) |
               (lr2 & 3);
      int c = kk * 4 + lg2;
      s16x8 vch = *(const s16x8*)&Lw[sp * 72 + c * 8];
      *(s16x8*)&KfT[(i * 64 + lane) * 8] = vch;
    }
  } else {
#pragma unroll
    for (int mf = 0; mf < 4; ++mf) {
      int m0 = mBase + mf * 16 + 4 * lg;
      int b = m0 >> 11, s0 = m0 & 2047;
      int kt = s0 >> 6, w0 = s0 & 63;
      int kkv = w0 >> 5, lg2 = (w0 >> 3) & 3, e0 = w0 & 7;
#pragma unroll
      for (int nf = 0; nf < 4; ++nf) {
        int col = nBase + nf * 16 + lr;
        int h = col >> 6;
        int bh = b * 16 + h;
        ushort4 pk;
        pk.x = f2bf(acc[mf][nf][0]); pk.y = f2bf(acc[mf][nf][1]);
        pk.z = f2bf(acc[mf][nf][2]); pk.w = f2bf(acc[mf][nf][3]);
        int idx2 = (((((bh * 32 + kt) * 4 + nf) * 2 + kkv) * 64) +
                    lg2 * 16 + lr) * 8 + e0;
        *(ushort4*)&Vf[idx2] = pk;
      }
    }
  }
}

// Flash attention: uniform blocks. grid 512: fid -> XCD-chunked bh (32) x
// pp (16). Each block runs q-tile 31-pp then pp (33 k-tiles total, same
// for all blocks -> no occupancy-decay tail). 4 waves = (q-half, k-parity);
// no LDS/barriers in the per-qt main loop; pairwise merge after each pass.
__global__ __launch_bounds__(256, 2) void attn(
    const unsigned short* __restrict__ Kf,  // frag layout
    const unsigned short* __restrict__ Vf,  // frag layout
    float* __restrict__ out) {              // [2][2048][1024]
  __shared__ float MB[2][2][4][16][17];
  __shared__ float ML[2][2][2][16];
  const float SC = 0.125f * 1.44269504088896f;  // scale * log2(e)
  const float THR = 44.0f;                      // ~= 8 / SC
  int tid = threadIdx.x;
  int fid = blockIdx.x;
  int bh = 4 * (fid & 7) + ((fid >> 3) & 3);
  int pp = fid >> 5;                            // 0..15
  int w = tid >> 6, lane = tid & 63, lr = lane & 15, lg = lane >> 4;
  int qh = w >> 1, par = w & 1;

  const unsigned short* KfB = Kf + (size_t)bh * 32 * 4096;
  const unsigned short* VfB = Vf + (size_t)bh * 32 * 4096;
  int b = bh >> 4, h = bh & 15;

  s16x8 kf[4][2], vf[4][2];
  auto loadK = [&](int kt_) {
#pragma unroll
    for (int nf = 0; nf < 4; ++nf)
#pragma unroll
      for (int kk = 0; kk < 2; ++kk)
        kf[nf][kk] = *(const s16x8*)
            &KfB[(((kt_ * 4 + nf) * 2 + kk) * 64 + lane) * 8];
  };
  auto loadV = [&](int kt_) {
#pragma unroll
    for (int nf = 0; nf < 4; ++nf)
#pragma unroll
      for (int kk = 0; kk < 2; ++kk)
        vf[nf][kk] = *(const s16x8*)
            &VfB[(((kt_ * 4 + nf) * 2 + kk) * 64 + lane) * 8];
  };

#pragma unroll 1
  for (int pass = 0; pass < 2; ++pass) {
    int qt = pass ? pp : (31 - pp);  // heavy tile first
    int q0 = qt * 64;

    // aq (B-operand) gathered from Kf.
    s16x8 aq[2][2];
#pragma unroll
    for (int qs = 0; qs < 2; ++qs) {
      int qr = q0 + qh * 32 + 16 * qs + lr;
      int ktq = qr >> 6, w64 = qr & 63;
      int nfq = ((w64 >> 5) << 1) | ((w64 >> 2) & 1);
      int r31 = w64 & 31;
      int lr2 = ((r31 >> 3) << 2) | (r31 & 3);
#pragma unroll
      for (int kk = 0; kk < 2; ++kk)
        aq[qs][kk] = *(const s16x8*)
            &KfB[((((ktq * 4 + nfq) * 2 + kk) * 64) + lg * 16 + lr2) * 8];
    }

    f32x4 o[2][4] = {};
    float m_[2] = {-1e30f, -1e30f}, l_[2] = {0.f, 0.f};

    int kt = par;
    bool active = kt <= qt;
    if (active) { loadK(kt); loadV(kt); }
    while (active) {
      f32x4 sa[2][4];
#pragma unroll
      for (int qs = 0; qs < 2; ++qs)
#pragma unroll
        for (int nf = 0; nf < 4; ++nf) sa[qs][nf] = (f32x4){0.f, 0.f, 0.f, 0.f};
#pragma unroll
      for (int kk = 0; kk < 2; ++kk)
#pragma unroll
        for (int nf = 0; nf < 4; ++nf)
#pragma unroll
          for (int qs = 0; qs < 2; ++qs)
            sa[qs][nf] = __builtin_amdgcn_mfma_f32_16x16x32_bf16(
                kf[nf][kk], aq[qs][kk], sa[qs][nf], 0, 0, 0);

      int ktn = kt + 2;
      bool more = ktn <= qt;
      if (more) loadK(ktn);  // pipelined: lands during softmax+PV

      if (kt == qt) {
#pragma unroll
        for (int qs = 0; qs < 2; ++qs) {
          int qglob = q0 + qh * 32 + 16 * qs + lr;
#pragma unroll
          for (int nf = 0; nf < 4; ++nf) {
            int kc = kt * 64 + 8 * lg + 4 * (nf & 1) + 32 * (nf >> 1);
#pragma unroll
            for (int j = 0; j < 4; ++j)
              if (kc + j > qglob) sa[qs][nf][j] = -3e38f;
          }
        }
      }
      float tm[2];
      float worst = -3e38f;
#pragma unroll
      for (int qs = 0; qs < 2; ++qs) {
        float t = sa[qs][0][0];
#pragma unroll
        for (int nf = 0; nf < 4; ++nf)
#pragma unroll
          for (int j = 0; j < 4; ++j) t = fmaxf(t, sa[qs][nf][j]);
        tm[qs] = t;
        worst = fmaxf(worst, t - m_[qs]);
      }
      if (!__all(worst <= THR)) {  // rare after first tile
#pragma unroll
        for (int qs = 0; qs < 2; ++qs) {
          float rm = fmaxf(tm[qs], __shfl_xor(tm[qs], 16));
          rm = fmaxf(rm, __shfl_xor(rm, 32));
          float mn = fmaxf(m_[qs], rm);
          float alpha = exp2f((m_[qs] - mn) * SC);
          m_[qs] = mn; l_[qs] *= alpha;
#pragma unroll
          for (int j = 0; j < 4; ++j) {
            float aj = __shfl(alpha, 4 * lg + j);
#pragma unroll
            for (int nf = 0; nf < 4; ++nf) o[qs][nf][j] *= aj;
          }
        }
      }
      unsigned cpk[2][8];
#pragma unroll
      for (int qs = 0; qs < 2; ++qs) {
        float msc = m_[qs] * SC;
#pragma unroll
        for (int nf = 0; nf < 4; ++nf) {
          float p0 = exp2f(fmaf(sa[qs][nf][0], SC, -msc));
          float p1 = exp2f(fmaf(sa[qs][nf][1], SC, -msc));
          float p2 = exp2f(fmaf(sa[qs][nf][2], SC, -msc));
          float p3 = exp2f(fmaf(sa[qs][nf][3], SC, -msc));
          l_[qs] += (p0 + p1) + (p2 + p3);
          unsigned r0, r1;
          asm("v_cvt_pk_bf16_f32 %0, %1, %2" : "=v"(r0) : "v"(p0), "v"(p1));
          asm("v_cvt_pk_bf16_f32 %0, %1, %2" : "=v"(r1) : "v"(p2), "v"(p3));
          cpk[qs][nf * 2] = r0; cpk[qs][nf * 2 + 1] = r1;
        }
      }
      s16x8 pav[2][2];
#pragma unroll
      for (int qs = 0; qs < 2; ++qs)
#pragma unroll
        for (int kk = 0; kk < 2; ++kk) {
          union { unsigned u[4]; s16x8 v; } pa;
          pa.u[0] = cpk[qs][4 * kk + 0]; pa.u[1] = cpk[qs][4 * kk + 1];
          pa.u[2] = cpk[qs][4 * kk + 2]; pa.u[3] = cpk[qs][4 * kk + 3];
          pav[qs][kk] = pa.v;
        }
#pragma unroll
      for (int kk = 0; kk < 2; ++kk)
#pragma unroll
        for (int nf = 0; nf < 4; ++nf)
#pragma unroll
          for (int qs = 0; qs < 2; ++qs)
            o[qs][nf] = __builtin_amdgcn_mfma_f32_16x16x32_bf16(
                pav[qs][kk], vf[nf][kk], o[qs][nf], 0, 0, 0);
      if (more) loadV(ktn);  // lands during next QK^T+softmax
      kt = ktn; active = more;
    }

    // pairwise merge: waves (qh,0) and (qh,1) share q-rows.
#pragma unroll
    for (int qs = 0; qs < 2; ++qs) {
      float t = l_[qs];
      t += __shfl_xor(t, 16); t += __shfl_xor(t, 32);
      l_[qs] = t;
    }
    if (par) {
#pragma unroll
      for (int qs = 0; qs < 2; ++qs) {
#pragma unroll
        for (int nf = 0; nf < 4; ++nf)
#pragma unroll
          for (int j = 0; j < 4; ++j)
            MB[qh][qs][nf][4 * lg + j][lr] = o[qs][nf][j];
        if (lg == 0) {
          ML[qh][qs][0][lr] = m_[qs];
          ML[qh][qs][1][lr] = l_[qs];
        }
      }
    }
    __syncthreads();
    if (!par) {
#pragma unroll
      for (int qs = 0; qs < 2; ++qs) {
        float m1 = ML[qh][qs][0][lr];
        float l1 = ML[qh][qs][1][lr];
        float ms = fmaxf(m_[qs], m1);
        float a0 = exp2f((m_[qs] - ms) * SC), a1 = exp2f((m1 - ms) * SC);
        float inv = 1.0f / (a0 * l_[qs] + a1 * l1);
#pragma unroll
        for (int j = 0; j < 4; ++j) {
          float c0 = __shfl(a0 * inv, 4 * lg + j);
          float c1 = __shfl(a1 * inv, 4 * lg + j);
#pragma unroll
          for (int nf = 0; nf < 4; ++nf) {
            float o1 = MB[qh][qs][nf][4 * lg + j][lr];
            int q = q0 + qh * 32 + 16 * qs + 4 * lg + j;
            out[(b * 2048 + q) * 1024 + h * 64 + nf * 16 + lr] =
                c0 * o[qs][nf][j] + c1 * o1;
          }
        }
      }
    }
    __syncthreads();  // MB/ML safe to reuse in next pass
  }
}

extern "C" void kernel_launch(void* const* d_in, const int* in_sizes, int n_in,
                              void* d_out, int out_size, void* d_ws, size_t ws_size,
                              hipStream_t stream) {
  const float* x = (const float*)d_in[0];
  const float* Wq = (const float*)d_in[1];
  const float* Wv = (const float*)d_in[2];
  const float* cosT = (const float*)d_in[3];
  const float* sinT = (const float*)d_in[4];
  float* out = (float*)d_out;

  unsigned short* xb = (unsigned short*)d_ws;        // 4M shorts
  unsigned short* wqb = xb + 4 * 1024 * 1024;        // 1M
  unsigned short* wvb = wqb + 1024 * 1024;           // 1M
  unsigned short* Kfb = wvb + 1024 * 1024;           // 4M (frag-layout RoPE'd Q==K)
  unsigned short* Vfb = Kfb + 4 * 1024 * 1024;       // 4M (frag-layout V)

  convert_all<<<6144, 256, 0, stream>>>(x, Wq, Wv, xb, wqb, wvb);
  qv_gemm<<<512, 256, 0, stream>>>(xb, wqb, wvb, cosT, sinT, Kfb, Vfb);
  attn<<<512, 256, 0, stream>>>(Kfb, Vfb, out);
}